// Round 4
// baseline (138.262 us; speedup 1.0000x reference)
//
#include <hip/hip_runtime.h>
#include <math.h>

#define NQ    12
#define DIM   4096        // 2^NQ
#define K_EXT 4096        // hi-only bf16 row
#define KSL   512         // K per slice (8 slices)
#define NSAMP 2048
#define NLAY  3
#define NT2   16          // 2048/128 tiles per dimension
#define NTRI2 136         // NT2*(NT2+1)/2 triangular tiles
#define NSLICE 8
#define BK    64

typedef __attribute__((ext_vector_type(8)))  short bf16x8;   // 8 bf16 = 4 VGPRs
typedef __attribute__((ext_vector_type(16))) float floatx16; // MFMA 32x32 acc

__device__ __forceinline__ unsigned short f32_to_bf16(float x) {
    unsigned u = __builtin_bit_cast(unsigned, x);
    u += 0x7FFFu + ((u >> 16) & 1u);            // round-to-nearest-even
    return (unsigned short)(u >> 16);
}

// async global->LDS, 16 B per lane; LDS dest = wave-uniform base + lane*16
__device__ __forceinline__ void gl_lds16(const unsigned short* g, unsigned short* l) {
    __builtin_amdgcn_global_load_lds(
        (const __attribute__((address_space(1))) unsigned int*)g,
        (__attribute__((address_space(3))) unsigned int*)l,
        16, 0, 0);
}

__device__ __forceinline__ void tri_decode(int bid, int& bi, int& bj) {
    int i = (int)((33.0 - sqrt(33.0*33.0 - 8.0*(double)bid)) * 0.5);
    int start = i*(33-i)/2;
    while (bid < start)               { --i; start = i*(33-i)/2; }
    while (bid >= start + (NT2 - i))  { start += NT2 - i; ++i; }
    bi = i; bj = i + (bid - start);
}

// ---------------------------------------------------------------------------
// Kernel 1: simulator.  Layer 0 is now CLOSED-FORM: on |0..0> the RY layer
// yields a product state amp(i) = prod_q f_q(bit_q(i)); built directly in
// Map1 via a 5-bit subset-product DP (+ exact CZ parity sign) — replaces a
// generic layer (~1100 VALU + 1 LDS transpose + 2 barriers) with ~100 VALU.
// Layers 1,2 and the epilogue are byte-identical to the verified version.
// Block 0 also zeroes the fused-reduce accumulators (stream-ordered).
// ---------------------------------------------------------------------------
__global__ __launch_bounds__(256) void sim_kernel(const float* __restrict__ data,
                                                  const float* __restrict__ params,
                                                  unsigned short* __restrict__ pe,
                                                  double* __restrict__ acc,
                                                  unsigned* __restrict__ cnt)
{
    __shared__ float CS[2*36], SN[2*36];
    __shared__ float trans[2][4608];    // padded transpose buffer (18 KiB/sample)
    const int tid  = threadIdx.x;
    const int wave = tid >> 6, lane = tid & 63;
    const int sidx = wave >> 1;         // sample within block
    const int w    = wave & 1;
    const int smp  = blockIdx.x * 2 + sidx;

    if (blockIdx.x == 0 && tid == 0) {  // zero fused-reduce state for this iter
        acc[0] = 0.0; acc[1] = 0.0; cnt[0] = 0u;
    }

    if (w == 0 && lane < NLAY*NQ) {
        const int q = lane % NQ;
        const float th = 0.5f * (params[lane] + data[smp*NQ + q]);
        CS[sidx*36 + lane] = cosf(th);
        SN[sidx*36 + lane] = sinf(th);
    }
    __syncthreads();

    float v[32];

    float* buf = trans[sidx];
    float* wb  = buf + 36*lane + 2304*w;                         // writer base
    const float* rb = buf + ((lane>>2)&15) + 16*w + 36*(lane&3); // reader base

    // ---- layer 0 closed form, constructed in Map1 ----
    // Map1: i = (lane&3) | (r<<2) | (((lane>>2)&15)<<7) | (w<<11)
    {
        const float* cs = &CS[sidx*36];
        const float* sn = &SN[sidx*36];
        const int hi = (lane >> 2) & 15;
        float fx = ((lane & 1) ? sn[0] : cs[0]) * ((lane & 2) ? sn[1] : cs[1]);
        fx *= ((hi & 1) ? sn[7]  : cs[7]);
        fx *= ((hi & 2) ? sn[8]  : cs[8]);
        fx *= ((hi & 4) ? sn[9]  : cs[9]);
        fx *= ((hi & 8) ? sn[10] : cs[10]);
        fx *= (w ? sn[11] : cs[11]);
        v[0] = fx * cs[2];
        v[1] = fx * sn[2];
        #pragma unroll
        for (int b = 1; b < 5; ++b) {
            const int M = 1 << b;
            #pragma unroll
            for (int r = 0; r < 32; ++r) {
                if (r < M) {
                    v[r | M] = v[r] * sn[2 + b];
                    v[r]     = v[r] * cs[2 + b];
                }
            }
        }
        // CZ ring sign (even-layer branch, shift=2) — identical parity code
        const int Base = (lane & 3) | (hi << 7) | (w << 11);
        #pragma unroll
        for (int r = 0; r < 32; ++r) {
            const int i  = Base | (r << 2);
            const int t  = ((i >> 1) | (i << 11)) & 0xFFF;
            const int p  = __popc(i & t) & 1;
            v[r] = __builtin_bit_cast(float, __builtin_bit_cast(int, v[r]) ^ (p << 31));
        }
    }

    #pragma unroll 1
    for (int l = 1; l < NLAY; ++l) {
        const float* cs = &CS[sidx*36 + l*NQ];
        const float* sn = &SN[sidx*36 + l*NQ];
        const int even = !(l & 1);       // even: state in Map0, else Map1

        // ---- first 5 register butterflies (q7-11 in Map0, q2-6 in Map1) ----
        {
            const int qb = even ? 7 : 2;
            #pragma unroll
            for (int b = 0; b < 5; ++b) {
                const float c = cs[qb + b], s = sn[qb + b];
                const int M = 1 << b;
                #pragma unroll
                for (int r = 0; r < 32; ++r) {
                    if (!(r & M)) {
                        const float a0 = v[r], a1 = v[r | M];
                        v[r]     = c * a0 - s * a1;
                        v[r | M] = s * a0 + c * a1;
                    }
                }
            }
        }
        // ---- qubits 0,1 (lane bits 0,1 in both maps): DPP quad_perm ----
        {
            const float c0 = cs[0], s0 = sn[0];
            const float t0 = (lane & 1) ? s0 : -s0;
            #pragma unroll
            for (int r = 0; r < 32; ++r) {
                const int iv = __builtin_bit_cast(int, v[r]);
                const int pv = __builtin_amdgcn_update_dpp(0, iv, 0xB1, 0xF, 0xF, true);
                v[r] = c0 * v[r] + t0 * __builtin_bit_cast(float, pv);
            }
            const float c1 = cs[1], s1 = sn[1];
            const float t1 = (lane & 2) ? s1 : -s1;
            #pragma unroll
            for (int r = 0; r < 32; ++r) {
                const int iv = __builtin_bit_cast(int, v[r]);
                const int pv = __builtin_amdgcn_update_dpp(0, iv, 0x4E, 0xF, 0xF, true);
                v[r] = c1 * v[r] + t1 * __builtin_bit_cast(float, pv);
            }
        }
        // ---- transpose: swap (lane bits 2-5, w) <-> register bits ----
        __syncthreads();                 // prior reads of buf complete
        #pragma unroll
        for (int t = 0; t < 8; ++t) {
            float4 q4;
            q4.x = v[4*t]; q4.y = v[4*t+1]; q4.z = v[4*t+2]; q4.w = v[4*t+3];
            *(float4*)&wb[4*t] = q4;
        }
        __syncthreads();
        #pragma unroll
        for (int r = 0; r < 32; ++r)
            v[r] = rb[144*(r & 15) + 2304*(r >> 4)];

        // ---- second 5 register butterflies (q2-6 if even, q7-11 if odd) ----
        {
            const int qb = even ? 2 : 7;
            #pragma unroll
            for (int b = 0; b < 5; ++b) {
                const float c = cs[qb + b], s = sn[qb + b];
                const int M = 1 << b;
                #pragma unroll
                for (int r = 0; r < 32; ++r) {
                    if (!(r & M)) {
                        const float a0 = v[r], a1 = v[r | M];
                        v[r]     = c * a0 - s * a1;
                        v[r | M] = s * a0 + c * a1;
                    }
                }
            }
        }
        // ---- CZ ring sign: exact parity from reconstructed index ----
        {
            const int Base = even ? ((lane & 3) | (((lane >> 2) & 15) << 7) | (w << 11))
                                  : (lane | (w << 6));
            const int shift = even ? 2 : 7;
            #pragma unroll
            for (int r = 0; r < 32; ++r) {
                const int i  = Base | (r << shift);
                const int t  = ((i >> 1) | (i << 11)) & 0xFFF;
                const int p  = __popc(i & t) & 1;
                v[r] = __builtin_bit_cast(float, __builtin_bit_cast(int, v[r]) ^ (p << 31));
            }
        }
    }

    // state ends in Map1 (3 layers).  k = (w*64+lane)*32 + r — a fixed
    // sample-independent permutation -> Gram-invariant.  hi bf16 only.
    const int sw = smp & 7;
    const int ell = w*64 + lane;
    unsigned short* outb = pe + (size_t)smp * K_EXT;
    #pragma unroll
    for (int c = 0; c < 4; ++c) {
        uint4 H;
        H.x = (unsigned)f32_to_bf16(v[c*8+0]) | ((unsigned)f32_to_bf16(v[c*8+1]) << 16);
        H.y = (unsigned)f32_to_bf16(v[c*8+2]) | ((unsigned)f32_to_bf16(v[c*8+3]) << 16);
        H.z = (unsigned)f32_to_bf16(v[c*8+4]) | ((unsigned)f32_to_bf16(v[c*8+5]) << 16);
        H.w = (unsigned)f32_to_bf16(v[c*8+6]) | ((unsigned)f32_to_bf16(v[c*8+7]) << 16);
        const int gc  = 4*ell + c;
        const int pos = (gc & ~7) | ((gc ^ sw) & 7);   // chunk swizzle within 8-group
        *(uint4*)&outb[pos*8] = H;
    }
}

// ---------------------------------------------------------------------------
// Kernel 2a: partial Gram, double-buffered (verified R2/R3 structure).
// Untouched this round.
// ---------------------------------------------------------------------------
__global__ __launch_bounds__(256) void gram_partial(const unsigned short* __restrict__ pe,
                                                    float* __restrict__ Gp)
{
    __shared__ __align__(16) unsigned short stage[2][2*128*64];   // 2 x (A|B) = 64 KiB

    const int tid   = threadIdx.x;
    const int tile  = blockIdx.x >> 3;     // bi-major tile walk per XCD
    const int slice = blockIdx.x & 7;      // one K-slice per XCD (bid % 8)
    int bi, bj; tri_decode(tile, bi, bj);
    const int k0 = slice * KSL;

    const int wave = tid >> 6, lane = tid & 63;
    const int qr = (wave >> 1) * 64;   // quadrant row offset
    const int qc = (wave &  1) * 64;   // quadrant col offset
    const int mrow = lane & 31;
    const int chsel = lane >> 5;       // chunk half-select within 16-k group
    const int sw = mrow & 7;           // read-side swizzle key (= row&7)

    floatx16 c00, c01, c10, c11;
    #pragma unroll
    for (int i = 0; i < 16; ++i) { c00[i]=0.f; c01[i]=0.f; c10[i]=0.f; c11[i]=0.f; }

    const int mat  = wave >> 1;            // 0=A, 1=B
    const int half = wave & 1;
    const unsigned short* gbase = pe
        + ((size_t)((mat ? bj : bi)*128 + half*64 + (lane >> 3))) * K_EXT
        + k0 + (lane & 7)*8;
    const int lofs = mat*128*64 + half*64*64;   // within one buffer (ushort units)

    // prologue: stage K-step 0 into buf0
    {
        unsigned short* l = &stage[0][lofs];
        #pragma unroll
        for (int i = 0; i < 8; ++i)
            gl_lds16(gbase + (size_t)i*8*K_EXT, l + i*512);
    }
    __syncthreads();                       // vmcnt(0) drain: buf0 ready

    int cur = 0;
    #pragma unroll 1
    for (int kk = 0; kk < KSL; kk += BK) {
        // prefetch next K-step into the other buffer (skip on last step)
        if (kk + BK < KSL) {
            unsigned short* l = &stage[cur ^ 1][lofs];
            const unsigned short* g = gbase + kk + BK;
            #pragma unroll
            for (int i = 0; i < 8; ++i)
                gl_lds16(g + (size_t)i*8*K_EXT, l + i*512);
        }

        const unsigned short* As = &stage[cur][0];
        const unsigned short* Bs = &stage[cur][128*64];
        #pragma unroll
        for (int ks = 0; ks < 4; ++ks) {
            const int ch = (ks*2 + chsel) ^ sw;            // swizzled chunk
            const bf16x8 a0 = *(const bf16x8*)&As[(qr +      mrow)*64 + ch*8];
            const bf16x8 a1 = *(const bf16x8*)&As[(qr + 32 + mrow)*64 + ch*8];
            const bf16x8 b0 = *(const bf16x8*)&Bs[(qc +      mrow)*64 + ch*8];
            const bf16x8 b1 = *(const bf16x8*)&Bs[(qc + 32 + mrow)*64 + ch*8];
            c00 = __builtin_amdgcn_mfma_f32_32x32x16_bf16(a0, b0, c00, 0, 0, 0);
            c01 = __builtin_amdgcn_mfma_f32_32x32x16_bf16(a0, b1, c01, 0, 0, 0);
            c10 = __builtin_amdgcn_mfma_f32_32x32x16_bf16(a1, b0, c10, 0, 0, 0);
            c11 = __builtin_amdgcn_mfma_f32_32x32x16_bf16(a1, b1, c11, 0, 0, 0);
        }
        __syncthreads();   // drains this step's prefetch; cur free for overwrite
        cur ^= 1;
    }

    // Write partial G quadrants.  C/D layout (m74/m101).
    float* Gt = Gp + ((size_t)slice * NTRI2 + tile) * 16384;
    const int crow = chsel * 4;
    const int ccol = lane & 31;
    #pragma unroll
    for (int rr = 0; rr < 16; ++rr) {
        const int rl = (rr & 3) + 8*(rr >> 2) + crow;    // 0..31
        const int r0 = qr + rl,  r1 = qr + 32 + rl;
        const int cA = qc + ccol, cB = qc + 32 + ccol;
        Gt[r0*128 + cA] = c00[rr];
        Gt[r0*128 + cB] = c01[rr];
        Gt[r1*128 + cA] = c10[rr];
        Gt[r1*128 + cB] = c11[rr];
    }
}

// ---------------------------------------------------------------------------
// Kernel 2b (fused finalize): sum the 8 K-slice partials with float4 loads,
// square, weight, block-reduce, then f64 atomicAdd into 2 global accumulators.
// The LAST block (ticket counter) computes the output scalar -> d_out.
// square_sum_l = N^2 exactly, so out = s1 / (N * sqrt(s2)).
// ---------------------------------------------------------------------------
__global__ __launch_bounds__(256) void gram_reduce(const float* __restrict__ Gp,
                                                   const int* __restrict__ labels,
                                                   double* __restrict__ acc,
                                                   unsigned* __restrict__ cnt,
                                                   float* __restrict__ out)
{
    __shared__ float la[128], lb[128];
    __shared__ double red1[256], red2[256];
    const int tid  = threadIdx.x;
    const int tile = blockIdx.x >> 2;
    const int quar = blockIdx.x & 3;
    int bi, bj; tri_decode(tile, bi, bj);

    if (tid < 128) la[tid]       = 2.0f*(float)labels[bi*128 + tid]       - 1.0f;
    else           lb[tid - 128] = 2.0f*(float)labels[bj*128 + tid - 128] - 1.0f;
    __syncthreads();

    const size_t stride = (size_t)NTRI2 * 16384;
    const float* g0 = Gp + (size_t)tile * 16384 + quar * 4096;

    double s1 = 0.0, s2 = 0.0;
    #pragma unroll
    for (int u = 0; u < 4; ++u) {
        const int e = u*1024 + tid*4;        // float4-aligned, coalesced
        float4 g = make_float4(0.f, 0.f, 0.f, 0.f);
        #pragma unroll
        for (int s = 0; s < NSLICE; ++s) {
            const float4 t = *(const float4*)&g0[e + (size_t)s*stride];
            g.x += t.x; g.y += t.y; g.z += t.z; g.w += t.w;
        }
        const int ge  = quar*4096 + e;
        const int row = ge >> 7, c0 = ge & 127;   // float4 never crosses a row
        const float lr = la[row];
        const float gg[4] = {g.x, g.y, g.z, g.w};
        #pragma unroll
        for (int j = 0; j < 4; ++j) {
            const int col = c0 + j;
            const float w = (bi < bj) ? 2.0f : ((row < col) ? 2.0f : ((row == col) ? 1.0f : 0.0f));
            const float g2 = gg[j] * gg[j];
            s1 += (double)(w * lr * lb[col] * g2);
            const double d = (double)g2;
            s2 += (double)w * d * d;
        }
    }

    red1[tid] = s1; red2[tid] = s2; __syncthreads();
    for (int off = 128; off; off >>= 1) {
        if (tid < off) { red1[tid] += red1[tid+off]; red2[tid] += red2[tid+off]; }
        __syncthreads();
    }
    if (tid == 0) {
        atomicAdd(&acc[0], red1[0]);
        atomicAdd(&acc[1], red2[0]);
        __threadfence();                     // adds visible device-wide before ticket
        const unsigned old = atomicAdd(cnt, 1u);
        if (old == NTRI2*4 - 1) {            // last block finalizes
            const double t1 = atomicAdd(&acc[0], 0.0);   // coherent read
            const double t2 = atomicAdd(&acc[1], 0.0);
            out[0] = (float)(t1 / (sqrt(t2) * (double)NSAMP));
        }
    }
}

// ---------------------------------------------------------------------------
extern "C" void kernel_launch(void* const* d_in, const int* in_sizes, int n_in,
                              void* d_out, int out_size, void* d_ws, size_t ws_size,
                              hipStream_t stream)
{
    const float* data   = (const float*)d_in[0]; // (2048,12) f32
    const int*   labels = (const int*)d_in[1];   // (2048,)   i32
    const float* params = (const float*)d_in[2]; // (3,12)    f32

    double*   acc = (double*)d_ws;                                    // [0]=s1,[1]=s2
    unsigned* cnt = (unsigned*)((char*)d_ws + 64);                    // ticket counter
    unsigned short* psi = (unsigned short*)((char*)d_ws + 16384);     // 16 MiB
    float* Gp = (float*)((char*)d_ws + 16384 + (size_t)NSAMP*K_EXT*2);// 8x136x16384 f32 = 71.3 MiB

    sim_kernel<<<NSAMP/2, 256, 0, stream>>>(data, params, psi, acc, cnt);
    gram_partial<<<NTRI2*NSLICE, 256, 0, stream>>>(psi, Gp);
    gram_reduce<<<NTRI2*4, 256, 0, stream>>>(Gp, labels, acc, cnt, (float*)d_out);
}

// Round 5
// 123.855 us; speedup vs baseline: 1.1163x; 1.1163x over previous
//
#include <hip/hip_runtime.h>
#include <math.h>

#define NQ    12
#define DIM   4096        // 2^NQ
#define K_EXT 4096        // hi-only bf16 row
#define KSL   1024        // K per slice (4 slices)
#define NSAMP 2048
#define NLAY  3
#define NT2   16          // 2048/128 tiles per dimension
#define NTRI2 136         // NT2*(NT2+1)/2 triangular tiles
#define NSLICE 4
#define BK    64

typedef __attribute__((ext_vector_type(8)))  short bf16x8;   // 8 bf16 = 4 VGPRs
typedef __attribute__((ext_vector_type(16))) float floatx16; // MFMA 32x32 acc

__device__ __forceinline__ unsigned short f32_to_bf16(float x) {
    unsigned u = __builtin_bit_cast(unsigned, x);
    u += 0x7FFFu + ((u >> 16) & 1u);            // round-to-nearest-even
    return (unsigned short)(u >> 16);
}

// async global->LDS, 16 B per lane; LDS dest = wave-uniform base + lane*16
__device__ __forceinline__ void gl_lds16(const unsigned short* g, unsigned short* l) {
    __builtin_amdgcn_global_load_lds(
        (const __attribute__((address_space(1))) unsigned int*)g,
        (__attribute__((address_space(3))) unsigned int*)l,
        16, 0, 0);
}

__device__ __forceinline__ void tri_decode(int bid, int& bi, int& bj) {
    int i = (int)((33.0 - sqrt(33.0*33.0 - 8.0*(double)bid)) * 0.5);
    int start = i*(33-i)/2;
    while (bid < start)               { --i; start = i*(33-i)/2; }
    while (bid >= start + (NT2 - i))  { start += NT2 - i; ++i; }
    bi = i; bj = i + (bid - start);
}

// ---------------------------------------------------------------------------
// Kernel 1: simulator.  Layer 0 CLOSED-FORM (verified passing in R4): on
// |0..0> the RY layer yields a product state amp(i) = prod_q f_q(bit_q(i)),
// built directly in Map1 via a 5-bit subset-product DP + exact CZ parity.
// Layers 1,2 and the epilogue are byte-identical to the verified version.
// ---------------------------------------------------------------------------
__global__ __launch_bounds__(256) void sim_kernel(const float* __restrict__ data,
                                                  const float* __restrict__ params,
                                                  unsigned short* __restrict__ pe)
{
    __shared__ float CS[2*36], SN[2*36];
    __shared__ float trans[2][4608];    // padded transpose buffer (18 KiB/sample)
    const int tid  = threadIdx.x;
    const int wave = tid >> 6, lane = tid & 63;
    const int sidx = wave >> 1;         // sample within block
    const int w    = wave & 1;
    const int smp  = blockIdx.x * 2 + sidx;

    if (w == 0 && lane < NLAY*NQ) {
        const int q = lane % NQ;
        const float th = 0.5f * (params[lane] + data[smp*NQ + q]);
        CS[sidx*36 + lane] = cosf(th);
        SN[sidx*36 + lane] = sinf(th);
    }
    __syncthreads();

    float v[32];

    float* buf = trans[sidx];
    float* wb  = buf + 36*lane + 2304*w;                         // writer base
    const float* rb = buf + ((lane>>2)&15) + 16*w + 36*(lane&3); // reader base

    // ---- layer 0 closed form, constructed in Map1 ----
    // Map1: i = (lane&3) | (r<<2) | (((lane>>2)&15)<<7) | (w<<11)
    {
        const float* cs = &CS[sidx*36];
        const float* sn = &SN[sidx*36];
        const int hi = (lane >> 2) & 15;
        float fx = ((lane & 1) ? sn[0] : cs[0]) * ((lane & 2) ? sn[1] : cs[1]);
        fx *= ((hi & 1) ? sn[7]  : cs[7]);
        fx *= ((hi & 2) ? sn[8]  : cs[8]);
        fx *= ((hi & 4) ? sn[9]  : cs[9]);
        fx *= ((hi & 8) ? sn[10] : cs[10]);
        fx *= (w ? sn[11] : cs[11]);
        v[0] = fx * cs[2];
        v[1] = fx * sn[2];
        #pragma unroll
        for (int b = 1; b < 5; ++b) {
            const int M = 1 << b;
            #pragma unroll
            for (int r = 0; r < 32; ++r) {
                if (r < M) {
                    v[r | M] = v[r] * sn[2 + b];
                    v[r]     = v[r] * cs[2 + b];
                }
            }
        }
        // CZ ring sign (even-layer branch, shift=2) — identical parity code
        const int Base = (lane & 3) | (hi << 7) | (w << 11);
        #pragma unroll
        for (int r = 0; r < 32; ++r) {
            const int i  = Base | (r << 2);
            const int t  = ((i >> 1) | (i << 11)) & 0xFFF;
            const int p  = __popc(i & t) & 1;
            v[r] = __builtin_bit_cast(float, __builtin_bit_cast(int, v[r]) ^ (p << 31));
        }
    }

    #pragma unroll 1
    for (int l = 1; l < NLAY; ++l) {
        const float* cs = &CS[sidx*36 + l*NQ];
        const float* sn = &SN[sidx*36 + l*NQ];
        const int even = !(l & 1);       // even: state in Map0, else Map1

        // ---- first 5 register butterflies (q7-11 in Map0, q2-6 in Map1) ----
        {
            const int qb = even ? 7 : 2;
            #pragma unroll
            for (int b = 0; b < 5; ++b) {
                const float c = cs[qb + b], s = sn[qb + b];
                const int M = 1 << b;
                #pragma unroll
                for (int r = 0; r < 32; ++r) {
                    if (!(r & M)) {
                        const float a0 = v[r], a1 = v[r | M];
                        v[r]     = c * a0 - s * a1;
                        v[r | M] = s * a0 + c * a1;
                    }
                }
            }
        }
        // ---- qubits 0,1 (lane bits 0,1 in both maps): DPP quad_perm ----
        {
            const float c0 = cs[0], s0 = sn[0];
            const float t0 = (lane & 1) ? s0 : -s0;
            #pragma unroll
            for (int r = 0; r < 32; ++r) {
                const int iv = __builtin_bit_cast(int, v[r]);
                const int pv = __builtin_amdgcn_update_dpp(0, iv, 0xB1, 0xF, 0xF, true);
                v[r] = c0 * v[r] + t0 * __builtin_bit_cast(float, pv);
            }
            const float c1 = cs[1], s1 = sn[1];
            const float t1 = (lane & 2) ? s1 : -s1;
            #pragma unroll
            for (int r = 0; r < 32; ++r) {
                const int iv = __builtin_bit_cast(int, v[r]);
                const int pv = __builtin_amdgcn_update_dpp(0, iv, 0x4E, 0xF, 0xF, true);
                v[r] = c1 * v[r] + t1 * __builtin_bit_cast(float, pv);
            }
        }
        // ---- transpose: swap (lane bits 2-5, w) <-> register bits ----
        __syncthreads();                 // prior reads of buf complete
        #pragma unroll
        for (int t = 0; t < 8; ++t) {
            float4 q4;
            q4.x = v[4*t]; q4.y = v[4*t+1]; q4.z = v[4*t+2]; q4.w = v[4*t+3];
            *(float4*)&wb[4*t] = q4;
        }
        __syncthreads();
        #pragma unroll
        for (int r = 0; r < 32; ++r)
            v[r] = rb[144*(r & 15) + 2304*(r >> 4)];

        // ---- second 5 register butterflies (q2-6 if even, q7-11 if odd) ----
        {
            const int qb = even ? 2 : 7;
            #pragma unroll
            for (int b = 0; b < 5; ++b) {
                const float c = cs[qb + b], s = sn[qb + b];
                const int M = 1 << b;
                #pragma unroll
                for (int r = 0; r < 32; ++r) {
                    if (!(r & M)) {
                        const float a0 = v[r], a1 = v[r | M];
                        v[r]     = c * a0 - s * a1;
                        v[r | M] = s * a0 + c * a1;
                    }
                }
            }
        }
        // ---- CZ ring sign: exact parity from reconstructed index ----
        {
            const int Base = even ? ((lane & 3) | (((lane >> 2) & 15) << 7) | (w << 11))
                                  : (lane | (w << 6));
            const int shift = even ? 2 : 7;
            #pragma unroll
            for (int r = 0; r < 32; ++r) {
                const int i  = Base | (r << shift);
                const int t  = ((i >> 1) | (i << 11)) & 0xFFF;
                const int p  = __popc(i & t) & 1;
                v[r] = __builtin_bit_cast(float, __builtin_bit_cast(int, v[r]) ^ (p << 31));
            }
        }
    }

    // state ends in Map1 (3 layers).  k = (w*64+lane)*32 + r — a fixed
    // sample-independent permutation -> Gram-invariant.  hi bf16 only.
    const int sw = smp & 7;
    const int ell = w*64 + lane;
    unsigned short* outb = pe + (size_t)smp * K_EXT;
    #pragma unroll
    for (int c = 0; c < 4; ++c) {
        uint4 H;
        H.x = (unsigned)f32_to_bf16(v[c*8+0]) | ((unsigned)f32_to_bf16(v[c*8+1]) << 16);
        H.y = (unsigned)f32_to_bf16(v[c*8+2]) | ((unsigned)f32_to_bf16(v[c*8+3]) << 16);
        H.z = (unsigned)f32_to_bf16(v[c*8+4]) | ((unsigned)f32_to_bf16(v[c*8+5]) << 16);
        H.w = (unsigned)f32_to_bf16(v[c*8+6]) | ((unsigned)f32_to_bf16(v[c*8+7]) << 16);
        const int gc  = 4*ell + c;
        const int pos = (gc & ~7) | ((gc ^ sw) & 7);   // chunk swizzle within 8-group
        *(uint4*)&outb[pos*8] = H;
    }
}

// ---------------------------------------------------------------------------
// Kernel 2a: partial Gram, double-buffered (verified R2/R3 structure).
// NSLICE 8->4: KSL=1024 -> 16 K-steps/block, 544 blocks (2/CU + small tail).
// Gp halves to 35.7 MiB (write traffic -34 MB).  Slice-per-XCD mapping kept:
// slice = bid&3, XCD = bid%8 -> XCDs {s, s+4} serve slice s (4 MiB/L2).
// All fragment addressing / chunk-XOR swizzle / accumulation order unchanged
// (k0 remains a multiple of BK, so the 8-chunk swizzle groups stay aligned).
// ---------------------------------------------------------------------------
__global__ __launch_bounds__(256) void gram_partial(const unsigned short* __restrict__ pe,
                                                    float* __restrict__ Gp)
{
    __shared__ __align__(16) unsigned short stage[2][2*128*64];   // 2 x (A|B) = 64 KiB

    const int tid   = threadIdx.x;
    const int tile  = blockIdx.x >> 2;     // bi-major tile walk per XCD
    const int slice = blockIdx.x & 3;      // K-slice
    int bi, bj; tri_decode(tile, bi, bj);
    const int k0 = slice * KSL;

    const int wave = tid >> 6, lane = tid & 63;
    const int qr = (wave >> 1) * 64;   // quadrant row offset
    const int qc = (wave &  1) * 64;   // quadrant col offset
    const int mrow = lane & 31;
    const int chsel = lane >> 5;       // chunk half-select within 16-k group
    const int sw = mrow & 7;           // read-side swizzle key (= row&7)

    floatx16 c00, c01, c10, c11;
    #pragma unroll
    for (int i = 0; i < 16; ++i) { c00[i]=0.f; c01[i]=0.f; c10[i]=0.f; c11[i]=0.f; }

    const int mat  = wave >> 1;            // 0=A, 1=B
    const int half = wave & 1;
    const unsigned short* gbase = pe
        + ((size_t)((mat ? bj : bi)*128 + half*64 + (lane >> 3))) * K_EXT
        + k0 + (lane & 7)*8;
    const int lofs = mat*128*64 + half*64*64;   // within one buffer (ushort units)

    // prologue: stage K-step 0 into buf0
    {
        unsigned short* l = &stage[0][lofs];
        #pragma unroll
        for (int i = 0; i < 8; ++i)
            gl_lds16(gbase + (size_t)i*8*K_EXT, l + i*512);
    }
    __syncthreads();                       // vmcnt(0) drain: buf0 ready

    int cur = 0;
    #pragma unroll 1
    for (int kk = 0; kk < KSL; kk += BK) {
        // prefetch next K-step into the other buffer (skip on last step)
        if (kk + BK < KSL) {
            unsigned short* l = &stage[cur ^ 1][lofs];
            const unsigned short* g = gbase + kk + BK;
            #pragma unroll
            for (int i = 0; i < 8; ++i)
                gl_lds16(g + (size_t)i*8*K_EXT, l + i*512);
        }

        const unsigned short* As = &stage[cur][0];
        const unsigned short* Bs = &stage[cur][128*64];
        #pragma unroll
        for (int ks = 0; ks < 4; ++ks) {
            const int ch = (ks*2 + chsel) ^ sw;            // swizzled chunk
            const bf16x8 a0 = *(const bf16x8*)&As[(qr +      mrow)*64 + ch*8];
            const bf16x8 a1 = *(const bf16x8*)&As[(qr + 32 + mrow)*64 + ch*8];
            const bf16x8 b0 = *(const bf16x8*)&Bs[(qc +      mrow)*64 + ch*8];
            const bf16x8 b1 = *(const bf16x8*)&Bs[(qc + 32 + mrow)*64 + ch*8];
            c00 = __builtin_amdgcn_mfma_f32_32x32x16_bf16(a0, b0, c00, 0, 0, 0);
            c01 = __builtin_amdgcn_mfma_f32_32x32x16_bf16(a0, b1, c01, 0, 0, 0);
            c10 = __builtin_amdgcn_mfma_f32_32x32x16_bf16(a1, b0, c10, 0, 0, 0);
            c11 = __builtin_amdgcn_mfma_f32_32x32x16_bf16(a1, b1, c11, 0, 0, 0);
        }
        __syncthreads();   // drains this step's prefetch; cur free for overwrite
        cur ^= 1;
    }

    // Write partial G quadrants.  C/D layout (m74/m101).
    float* Gt = Gp + ((size_t)slice * NTRI2 + tile) * 16384;
    const int crow = chsel * 4;
    const int ccol = lane & 31;
    #pragma unroll
    for (int rr = 0; rr < 16; ++rr) {
        const int rl = (rr & 3) + 8*(rr >> 2) + crow;    // 0..31
        const int r0 = qr + rl,  r1 = qr + 32 + rl;
        const int cA = qc + ccol, cB = qc + 32 + ccol;
        Gt[r0*128 + cA] = c00[rr];
        Gt[r0*128 + cB] = c01[rr];
        Gt[r1*128 + cA] = c10[rr];
        Gt[r1*128 + cB] = c11[rr];
    }
}

// ---------------------------------------------------------------------------
// Kernel 2b: sum the 4 K-slice partials, square, weight, reduce.
// R3 structure (plain stores to part1/part2, no atomics).
// ---------------------------------------------------------------------------
__global__ __launch_bounds__(256) void gram_reduce(const float* __restrict__ Gp,
                                                   const int* __restrict__ labels,
                                                   double* __restrict__ part1,
                                                   double* __restrict__ part2)
{
    __shared__ float la[128], lb[128];
    __shared__ double red[256];
    const int tid  = threadIdx.x;
    const int tile = blockIdx.x >> 2;
    const int quar = blockIdx.x & 3;
    int bi, bj; tri_decode(tile, bi, bj);

    if (tid < 128) la[tid]       = 2.0f*(float)labels[bi*128 + tid]       - 1.0f;
    else           lb[tid - 128] = 2.0f*(float)labels[bj*128 + tid - 128] - 1.0f;
    __syncthreads();

    const size_t stride = (size_t)NTRI2 * 16384;
    const float* g0 = Gp + (size_t)tile * 16384 + quar * 4096;

    double s1 = 0.0, s2 = 0.0;
    #pragma unroll 2
    for (int u = 0; u < 16; ++u) {
        const int e  = u*256 + tid;          // 0..4095 within quarter
        const int ge = quar*4096 + e;
        float g = 0.f;
        #pragma unroll
        for (int s = 0; s < NSLICE; ++s) g += g0[e + (size_t)s*stride];
        const int row = ge >> 7, col = ge & 127;
        const float w = (bi < bj) ? 2.0f : ((row < col) ? 2.0f : ((row == col) ? 1.0f : 0.0f));
        const float g2 = g * g;
        s1 += (double)(w * la[row] * lb[col] * g2);
        const double d = (double)g2;
        s2 += (double)w * d * d;
    }

    red[tid] = s1; __syncthreads();
    for (int off = 128; off; off >>= 1) { if (tid < off) red[tid] += red[tid+off]; __syncthreads(); }
    if (tid == 0) part1[blockIdx.x] = red[0];
    __syncthreads();
    red[tid] = s2; __syncthreads();
    for (int off = 128; off; off >>= 1) { if (tid < off) red[tid] += red[tid+off]; __syncthreads(); }
    if (tid == 0) part2[blockIdx.x] = red[0];
}

// ---------------------------------------------------------------------------
// Kernel 3: reduce 544 partial slots -> scalar f32.
// square_sum_l = N^2 exactly, so out = s1 / (N * sqrt(s2)).
// ---------------------------------------------------------------------------
__global__ __launch_bounds__(256) void finalize_kernel(const double* __restrict__ part1,
                                                       const double* __restrict__ part2,
                                                       float* __restrict__ out)
{
    __shared__ double r1[256], r2[256];
    const int tid = threadIdx.x;
    double a = 0.0, b = 0.0;
    #pragma unroll
    for (int u = 0; u < 3; ++u) {
        const int s = tid + u*256;
        if (s < NTRI2*4) { a += part1[s]; b += part2[s]; }
    }
    r1[tid] = a; r2[tid] = b; __syncthreads();
    for (int off = 128; off; off >>= 1) {
        if (tid < off) { r1[tid] += r1[tid+off]; r2[tid] += r2[tid+off]; }
        __syncthreads();
    }
    if (tid == 0) out[0] = (float)(r1[0] / (sqrt(r2[0]) * (double)NSAMP));
}

// ---------------------------------------------------------------------------
extern "C" void kernel_launch(void* const* d_in, const int* in_sizes, int n_in,
                              void* d_out, int out_size, void* d_ws, size_t ws_size,
                              hipStream_t stream)
{
    const float* data   = (const float*)d_in[0]; // (2048,12) f32
    const int*   labels = (const int*)d_in[1];   // (2048,)   i32
    const float* params = (const float*)d_in[2]; // (3,12)    f32

    double* part1 = (double*)d_ws;                                    // 544 (pad 768) doubles
    double* part2 = part1 + 768;                                      // 544 doubles
    unsigned short* psi = (unsigned short*)((char*)d_ws + 16384);     // 16 MiB
    float* Gp = (float*)((char*)d_ws + 16384 + (size_t)NSAMP*K_EXT*2);// 4x136x16384 f32 = 35.7 MiB

    sim_kernel<<<NSAMP/2, 256, 0, stream>>>(data, params, psi);
    gram_partial<<<NTRI2*NSLICE, 256, 0, stream>>>(psi, Gp);
    gram_reduce<<<NTRI2*4, 256, 0, stream>>>(Gp, labels, part1, part2);
    finalize_kernel<<<1, 256, 0, stream>>>(part1, part2, (float*)d_out);
}